// Round 1
// baseline (2490.500 us; speedup 1.0000x reference)
//
#include <hip/hip_runtime.h>

#define LEAKY(v) ((v) > 0.0f ? (v) : 0.01f * (v))

// ---------------------------------------------------------------------------
// Edge-index repack: handles both int32 and int64 on-device.
// int64 layout (little-endian, values < 2^31): odd 32-bit words are all 0.
// With int32 data, odd words are real indices (P(first 64 odd words all 0) ~ 0).
// ---------------------------------------------------------------------------
__global__ void repack_kernel(const unsigned* __restrict__ ei,
                              int* __restrict__ s32, int* __restrict__ d32, int E) {
    __shared__ int is64_s;
    if (threadIdx.x == 0) {
        int z = 1;
        int limit = 2 * E < 128 ? 2 * E : 128;
        for (int i = 1; i < limit; i += 2)
            if (ei[i] != 0u) { z = 0; break; }
        is64_s = z;
    }
    __syncthreads();
    const int is64 = is64_s;
    int e = blockIdx.x * blockDim.x + threadIdx.x;
    if (e < E) {
        if (is64) {
            s32[e] = (int)ei[2 * (long long)e];
            d32[e] = (int)ei[2 * ((long long)E + e)];
        } else {
            s32[e] = (int)ei[e];
            d32[e] = (int)ei[E + e];
        }
    }
}

__global__ void hist_kernel(const int* __restrict__ dst, int* __restrict__ deg, int E) {
    int e = blockIdx.x * blockDim.x + threadIdx.x;
    if (e < E) atomicAdd(&deg[dst[e]], 1);
}

__global__ void dinv_kernel(const int* __restrict__ deg, float* __restrict__ dinv, int N) {
    int i = blockIdx.x * blockDim.x + threadIdx.x;
    if (i < N) dinv[i] = rsqrtf((float)deg[i] + 1.0f);
}

__global__ void norm_kernel(const int* __restrict__ src, const int* __restrict__ dst,
                            const float* __restrict__ dinv, float* __restrict__ nrm, int E) {
    int e = blockIdx.x * blockDim.x + threadIdx.x;
    if (e < E) nrm[e] = dinv[src[e]] * dinv[dst[e]];
}

// h[n,m] = sum_k act(x[n,k]) * W[k,m].  W staged in LDS; a wave covers mostly
// one n (consecutive m) so x[n,k] loads broadcast from L1.
template <int K, int M, bool ACT>
__global__ void gemm_kernel(const float* __restrict__ x, const float* __restrict__ W,
                            float* __restrict__ h, int N) {
    __shared__ float ws[K * M];
    for (int i = threadIdx.x; i < K * M; i += blockDim.x) ws[i] = W[i];
    __syncthreads();
    int t = blockIdx.x * blockDim.x + threadIdx.x;
    if (t >= N * M) return;
    int n = t / M, m = t - n * M;
    const float* xr = x + (long long)n * K;
    float acc = 0.0f;
#pragma unroll
    for (int k = 0; k < K; ++k) {
        float xv = xr[k];
        if (ACT) xv = LEAKY(xv);
        acc = fmaf(xv, ws[k * M + m], acc);
    }
    h[t] = acc;
}

// agg[n,m] = h[n,m] * dinv[n]^2 + b[m]   (self-loop + bias as initializer)
template <int M>
__global__ void init_agg_kernel(const float* __restrict__ h, const float* __restrict__ dinv,
                                const float* __restrict__ b, float* __restrict__ agg, int N) {
    int t = blockIdx.x * blockDim.x + threadIdx.x;
    if (t >= N * M) return;
    int n = t / M, m = t - n * M;
    float di = dinv[n];
    agg[t] = fmaf(h[t], di * di, b[m]);
}

// agg[dst] += h[src] * norm[e], vectorized over features (VW floats/thread).
template <int F, int VW>
__global__ void scatter_kernel(const float* __restrict__ h, const float* __restrict__ nrm,
                               const int* __restrict__ src, const int* __restrict__ dst,
                               float* __restrict__ agg, int E) {
    constexpr int C = F / VW;
    int t = blockIdx.x * blockDim.x + threadIdx.x;
    if (t >= E * C) return;
    int e = t / C, c = t - e * C;
    int s = src[e], d = dst[e];
    float nm = nrm[e];
    const float* hp = h + (long long)s * F + c * VW;
    float* ap = agg + (long long)d * F + c * VW;
    if (VW == 4) {
        float4 hv = *(const float4*)hp;
        unsafeAtomicAdd(ap + 0, hv.x * nm);
        unsafeAtomicAdd(ap + 1, hv.y * nm);
        unsafeAtomicAdd(ap + 2, hv.z * nm);
        unsafeAtomicAdd(ap + 3, hv.w * nm);
    } else {
        float2 hv = *(const float2*)hp;
        unsafeAtomicAdd(ap + 0, hv.x * nm);
        unsafeAtomicAdd(ap + 1, hv.y * nm);
    }
}

// logits = leaky(a) @ Wl + bl; out = log_softmax(logits)
__global__ void head_kernel(const float* __restrict__ a, const float* __restrict__ Wl,
                            const float* __restrict__ bl, float* __restrict__ out, int N) {
    __shared__ float ws[50 * 10];
    __shared__ float bs[10];
    for (int i = threadIdx.x; i < 500; i += blockDim.x) ws[i] = Wl[i];
    if (threadIdx.x < 10) bs[threadIdx.x] = bl[threadIdx.x];
    __syncthreads();
    int n = blockIdx.x * blockDim.x + threadIdx.x;
    if (n >= N) return;
    float logits[10];
#pragma unroll
    for (int j = 0; j < 10; ++j) logits[j] = bs[j];
    const float* ar = a + (long long)n * 50;
#pragma unroll
    for (int k = 0; k < 50; ++k) {
        float v = LEAKY(ar[k]);
#pragma unroll
        for (int j = 0; j < 10; ++j) logits[j] = fmaf(v, ws[k * 10 + j], logits[j]);
    }
    float mx = logits[0];
#pragma unroll
    for (int j = 1; j < 10; ++j) mx = fmaxf(mx, logits[j]);
    float s = 0.0f;
#pragma unroll
    for (int j = 0; j < 10; ++j) s += __expf(logits[j] - mx);
    float lse = __logf(s) + mx;
    float* op = out + (long long)n * 10;
#pragma unroll
    for (int j = 0; j < 10; ++j) op[j] = logits[j] - lse;
}

extern "C" void kernel_launch(void* const* d_in, const int* in_sizes, int n_in,
                              void* d_out, int out_size, void* d_ws, size_t ws_size,
                              hipStream_t stream) {
    const float* x  = (const float*)d_in[0];
    const unsigned* ei = (const unsigned*)d_in[1];
    const float* W1 = (const float*)d_in[2];
    const float* b1 = (const float*)d_in[3];
    const float* W2 = (const float*)d_in[4];
    const float* b2 = (const float*)d_in[5];
    const float* W3 = (const float*)d_in[6];
    const float* b3 = (const float*)d_in[7];
    const float* Wl = (const float*)d_in[8];
    const float* bl = (const float*)d_in[9];
    float* out = (float*)d_out;

    const int N = in_sizes[0] / 64;
    const int E = in_sizes[1] / 2;

    // workspace layout (256B-aligned chunks)
    char* wp = (char*)d_ws;
    auto alloc = [&](size_t bytes) {
        char* p = wp;
        wp += (bytes + 255) & ~(size_t)255;
        return p;
    };
    int*   src  = (int*)alloc((size_t)E * 4);
    int*   dst  = (int*)alloc((size_t)E * 4);
    float* dinv = (float*)alloc((size_t)N * 4);
    float* nrm  = (float*)alloc((size_t)E * 4);
    int*   deg  = (int*)alloc((size_t)N * 4);
    float* H    = (float*)alloc((size_t)N * 80 * 4);
    float* A    = (float*)alloc((size_t)N * 80 * 4);

    const int B = 256;
    hipMemsetAsync(deg, 0, (size_t)N * 4, stream);
    repack_kernel<<<(E + B - 1) / B, B, 0, stream>>>(ei, src, dst, E);
    hist_kernel<<<(E + B - 1) / B, B, 0, stream>>>(dst, deg, E);
    dinv_kernel<<<(N + B - 1) / B, B, 0, stream>>>(deg, dinv, N);
    norm_kernel<<<(E + B - 1) / B, B, 0, stream>>>(src, dst, dinv, nrm, E);

    // layer 1: 64 -> 80
    gemm_kernel<64, 80, false><<<(N * 80 + B - 1) / B, B, 0, stream>>>(x, W1, H, N);
    init_agg_kernel<80><<<(N * 80 + B - 1) / B, B, 0, stream>>>(H, dinv, b1, A, N);
    scatter_kernel<80, 4><<<(E * 20 + B - 1) / B, B, 0, stream>>>(H, nrm, src, dst, A, E);

    // layer 2: 80 -> 40 (leaky on load of A)
    gemm_kernel<80, 40, true><<<(N * 40 + B - 1) / B, B, 0, stream>>>(A, W2, H, N);
    init_agg_kernel<40><<<(N * 40 + B - 1) / B, B, 0, stream>>>(H, dinv, b2, A, N);
    scatter_kernel<40, 4><<<(E * 10 + B - 1) / B, B, 0, stream>>>(H, nrm, src, dst, A, E);

    // layer 3: 40 -> 50
    gemm_kernel<40, 50, true><<<(N * 50 + B - 1) / B, B, 0, stream>>>(A, W3, H, N);
    init_agg_kernel<50><<<(N * 50 + B - 1) / B, B, 0, stream>>>(H, dinv, b3, A, N);
    scatter_kernel<50, 2><<<(E * 25 + B - 1) / B, B, 0, stream>>>(H, nrm, src, dst, A, E);

    // head: leaky -> 50x10 linear -> log_softmax
    head_kernel<<<(N + B - 1) / B, B, 0, stream>>>(A, Wl, bl, out, N);
}

// Round 2
// 628.864 us; speedup vs baseline: 3.9603x; 3.9603x over previous
//
#include <hip/hip_runtime.h>

#define LEAKY(v) ((v) > 0.0f ? (v) : 0.01f * (v))
#define SCAN_B 256

// ---------------------------------------------------------------------------
// Edge-index repack: handles both int32 and int64 on-device.
// int64 little-endian with values < 2^31: odd 32-bit words are all 0.
// ---------------------------------------------------------------------------
__global__ void repack_kernel(const unsigned* __restrict__ ei,
                              int* __restrict__ s32, int* __restrict__ d32, int E) {
    __shared__ int is64_s;
    if (threadIdx.x == 0) {
        int z = 1;
        int limit = 2 * E < 128 ? 2 * E : 128;
        for (int i = 1; i < limit; i += 2)
            if (ei[i] != 0u) { z = 0; break; }
        is64_s = z;
    }
    __syncthreads();
    const int is64 = is64_s;
    int e = blockIdx.x * blockDim.x + threadIdx.x;
    if (e < E) {
        if (is64) {
            s32[e] = (int)ei[2 * (long long)e];
            d32[e] = (int)ei[2 * ((long long)E + e)];
        } else {
            s32[e] = (int)ei[e];
            d32[e] = (int)ei[E + e];
        }
    }
}

__global__ void hist_kernel(const int* __restrict__ dst, int* __restrict__ deg, int E) {
    int e = blockIdx.x * blockDim.x + threadIdx.x;
    if (e < E) atomicAdd(&deg[dst[e]], 1);
}

__global__ void dinv_kernel(const int* __restrict__ deg, float* __restrict__ dinv, int N) {
    int i = blockIdx.x * blockDim.x + threadIdx.x;
    if (i < N) dinv[i] = rsqrtf((float)deg[i] + 1.0f);
}

// ---- two-level exclusive scan of deg -> row_ofs (CSR), cur = copy ----------
__global__ void block_sum_kernel(const int* __restrict__ deg, int* __restrict__ blk, int N) {
    __shared__ int s[SCAN_B];
    int i = blockIdx.x * SCAN_B + threadIdx.x;
    s[threadIdx.x] = (i < N) ? deg[i] : 0;
    __syncthreads();
    for (int off = SCAN_B / 2; off > 0; off >>= 1) {
        if (threadIdx.x < off) s[threadIdx.x] += s[threadIdx.x + off];
        __syncthreads();
    }
    if (threadIdx.x == 0) blk[blockIdx.x] = s[0];
}

// single block, 512 threads: exclusive scan of blk[0..nb), nb <= 512
__global__ void scan_blocks_kernel(int* __restrict__ blk, int nb) {
    __shared__ int s[512];
    int t = threadIdx.x;
    s[t] = (t < nb) ? blk[t] : 0;
    __syncthreads();
    for (int off = 1; off < 512; off <<= 1) {
        int add = (t >= off) ? s[t - off] : 0;
        __syncthreads();
        s[t] += add;
        __syncthreads();
    }
    if (t < nb) blk[t] = (t == 0) ? 0 : s[t - 1];
}

__global__ void row_ofs_kernel(const int* __restrict__ deg, const int* __restrict__ blk_ofs,
                               int* __restrict__ row_ofs, int* __restrict__ cur, int N, int E) {
    __shared__ int s[SCAN_B];
    int t = threadIdx.x;
    int i = blockIdx.x * SCAN_B + t;
    int d = (i < N) ? deg[i] : 0;
    s[t] = d;
    __syncthreads();
    for (int off = 1; off < SCAN_B; off <<= 1) {
        int add = (t >= off) ? s[t - off] : 0;
        __syncthreads();
        s[t] += add;
        __syncthreads();
    }
    int ro = blk_ofs[blockIdx.x] + s[t] - d;  // exclusive prefix
    if (i < N) {
        row_ofs[i] = ro;
        cur[i] = ro;
        if (i == N - 1) row_ofs[N] = E;
    }
}

// fill CSR payload: es[p] = {src (bit-cast), norm = dinv[src]*dinv[dst]}
__global__ void fill_kernel(const int* __restrict__ src, const int* __restrict__ dst,
                            const float* __restrict__ dinv, int* __restrict__ cur,
                            float2* __restrict__ es, int E) {
    int e = blockIdx.x * blockDim.x + threadIdx.x;
    if (e < E) {
        int s = src[e], d = dst[e];
        int p = atomicAdd(&cur[d], 1);
        es[p] = make_float2(__int_as_float(s), dinv[s] * dinv[d]);
    }
}

// ---------------------------------------------------------------------------
// Gather aggregation: one wave per node, lanes cover features.
//   agg[n] = sum_{e in in(n)} act(h[src_e]) * nrm_e  +  act(h[n]) * dinv[n]^2 (+ b)
// ---------------------------------------------------------------------------
template <int F, bool ACT, bool BIAS>
__global__ void gather_kernel(const float* __restrict__ h, const float2* __restrict__ es,
                              const int* __restrict__ row_ofs, const float* __restrict__ dinv,
                              const float* __restrict__ b, float* __restrict__ agg, int N) {
    constexpr int C = (F + 63) / 64;
    int gid = blockIdx.x * blockDim.x + threadIdx.x;
    int node = gid >> 6;
    int lane = threadIdx.x & 63;
    if (node >= N) return;
    int beg = row_ofs[node], end = row_ofs[node + 1];
    float di = dinv[node];
    const float* hrow = h + (long long)node * F;
    float acc[C];
#pragma unroll
    for (int c = 0; c < C; ++c) {
        int f = lane + 64 * c;
        if (f < F) {
            float v = hrow[f];
            if (ACT) v = LEAKY(v);
            acc[c] = BIAS ? fmaf(v, di * di, b[f]) : v * di * di;
        } else acc[c] = 0.0f;
    }
    // software pipeline: prefetch next edge descriptor
    float2 e;
    if (beg < end) e = es[beg];
    for (int j = beg; j < end; ++j) {
        float2 ec = e;
        if (j + 1 < end) e = es[j + 1];
        int s = __float_as_int(ec.x);
        float nm = ec.y;
        const float* hs = h + (long long)s * F;
#pragma unroll
        for (int c = 0; c < C; ++c) {
            int f = lane + 64 * c;
            if (f < F) {
                float v = hs[f];
                if (ACT) v = LEAKY(v);
                acc[c] = fmaf(v, nm, acc[c]);
            }
        }
    }
    float* arow = agg + (long long)node * F;
#pragma unroll
    for (int c = 0; c < C; ++c) {
        int f = lane + 64 * c;
        if (f < F) arow[f] = acc[c];
    }
}

// h[n,m] = sum_k act(x[n,k]) * W[k,m] (+ b[m]).  W staged in LDS.
template <int K, int M, bool ACT, bool BIAS>
__global__ void gemm_kernel(const float* __restrict__ x, const float* __restrict__ W,
                            const float* __restrict__ b, float* __restrict__ h, int N) {
    __shared__ float ws[K * M];
    for (int i = threadIdx.x; i < K * M; i += blockDim.x) ws[i] = W[i];
    __syncthreads();
    int t = blockIdx.x * blockDim.x + threadIdx.x;
    if (t >= N * M) return;
    int n = t / M, m = t - n * M;
    const float* xr = x + (long long)n * K;
    float acc = BIAS ? b[m] : 0.0f;
#pragma unroll
    for (int k = 0; k < K; ++k) {
        float xv = xr[k];
        if (ACT) xv = LEAKY(xv);
        acc = fmaf(xv, ws[k * M + m], acc);
    }
    h[t] = acc;
}

// logits = leaky(a) @ Wl + bl; out = log_softmax(logits)
__global__ void head_kernel(const float* __restrict__ a, const float* __restrict__ Wl,
                            const float* __restrict__ bl, float* __restrict__ out, int N) {
    __shared__ float ws[50 * 10];
    __shared__ float bs[10];
    for (int i = threadIdx.x; i < 500; i += blockDim.x) ws[i] = Wl[i];
    if (threadIdx.x < 10) bs[threadIdx.x] = bl[threadIdx.x];
    __syncthreads();
    int n = blockIdx.x * blockDim.x + threadIdx.x;
    if (n >= N) return;
    float logits[10];
#pragma unroll
    for (int j = 0; j < 10; ++j) logits[j] = bs[j];
    const float* ar = a + (long long)n * 50;
#pragma unroll
    for (int k = 0; k < 50; ++k) {
        float v = LEAKY(ar[k]);
#pragma unroll
        for (int j = 0; j < 10; ++j) logits[j] = fmaf(v, ws[k * 10 + j], logits[j]);
    }
    float mx = logits[0];
#pragma unroll
    for (int j = 1; j < 10; ++j) mx = fmaxf(mx, logits[j]);
    float s = 0.0f;
#pragma unroll
    for (int j = 0; j < 10; ++j) s += __expf(logits[j] - mx);
    float lse = __logf(s) + mx;
    float* op = out + (long long)n * 10;
#pragma unroll
    for (int j = 0; j < 10; ++j) op[j] = logits[j] - lse;
}

extern "C" void kernel_launch(void* const* d_in, const int* in_sizes, int n_in,
                              void* d_out, int out_size, void* d_ws, size_t ws_size,
                              hipStream_t stream) {
    const float* x  = (const float*)d_in[0];
    const unsigned* ei = (const unsigned*)d_in[1];
    const float* W1 = (const float*)d_in[2];
    const float* b1 = (const float*)d_in[3];
    const float* W2 = (const float*)d_in[4];
    const float* b2 = (const float*)d_in[5];
    const float* W3 = (const float*)d_in[6];
    const float* b3 = (const float*)d_in[7];
    const float* Wl = (const float*)d_in[8];
    const float* bl = (const float*)d_in[9];
    float* out = (float*)d_out;

    const int N = in_sizes[0] / 64;
    const int E = in_sizes[1] / 2;

    char* wp = (char*)d_ws;
    auto alloc = [&](size_t bytes) {
        char* p = wp;
        wp += (bytes + 255) & ~(size_t)255;
        return p;
    };
    int*    src     = (int*)alloc((size_t)E * 4);
    int*    dst     = (int*)alloc((size_t)E * 4);
    float2* es      = (float2*)alloc((size_t)E * 8);
    int*    deg     = (int*)alloc((size_t)N * 4);
    float*  dinv    = (float*)alloc((size_t)N * 4);
    int*    row_ofs = (int*)alloc((size_t)(N + 1) * 4);
    int*    cur     = (int*)alloc((size_t)N * 4);
    int*    blk     = (int*)alloc((size_t)512 * 4);
    float*  P       = (float*)alloc((size_t)N * 64 * 4);  // narrow scratch (<=64 wide)
    float*  A       = (float*)alloc((size_t)N * 80 * 4);  // wide scratch (<=80 wide)

    const int B = 256;
    const int nb = (N + SCAN_B - 1) / SCAN_B;  // <= 512 for N <= 131072

    // ---- CSR build (reused by all 3 layers) ----
    hipMemsetAsync(deg, 0, (size_t)N * 4, stream);
    repack_kernel<<<(E + B - 1) / B, B, 0, stream>>>(ei, src, dst, E);
    hist_kernel<<<(E + B - 1) / B, B, 0, stream>>>(dst, deg, E);
    dinv_kernel<<<(N + B - 1) / B, B, 0, stream>>>(deg, dinv, N);
    block_sum_kernel<<<nb, SCAN_B, 0, stream>>>(deg, blk, N);
    scan_blocks_kernel<<<1, 512, 0, stream>>>(blk, nb);
    row_ofs_kernel<<<nb, SCAN_B, 0, stream>>>(deg, blk, row_ofs, cur, N, E);
    fill_kernel<<<(E + B - 1) / B, B, 0, stream>>>(src, dst, dinv, cur, es, E);

    const int gblocks = (N * 64 + B - 1) / B;  // one wave per node

    // L1: agg(x) first (64-wide < 80-wide), then GEMM(+b1)
    gather_kernel<64, false, false><<<gblocks, B, 0, stream>>>(x, es, row_ofs, dinv, nullptr, P, N);
    gemm_kernel<64, 80, false, true><<<(N * 80 + B - 1) / B, B, 0, stream>>>(P, W1, b1, A, N);

    // L2: GEMM first (40-wide < 80-wide): H = leaky(A) @ W2, then agg(+b2)
    gemm_kernel<80, 40, true, false><<<(N * 40 + B - 1) / B, B, 0, stream>>>(A, W2, nullptr, P, N);
    gather_kernel<40, false, true><<<gblocks, B, 0, stream>>>(P, es, row_ofs, dinv, b2, A, N);

    // L3: agg(leaky(A)) first (40-wide < 50-wide), then GEMM(+b3)
    gather_kernel<40, true, false><<<gblocks, B, 0, stream>>>(A, es, row_ofs, dinv, nullptr, P, N);
    gemm_kernel<40, 50, false, true><<<(N * 50 + B - 1) / B, B, 0, stream>>>(P, W3, b3, A, N);

    // head: leaky -> 50x10 linear -> log_softmax
    head_kernel<<<(N + B - 1) / B, B, 0, stream>>>(A, Wl, bl, out, N);
}

// Round 3
// 506.215 us; speedup vs baseline: 4.9198x; 1.2423x over previous
//
#include <hip/hip_runtime.h>

#define LEAKY(v) ((v) > 0.0f ? (v) : 0.01f * (v))
#define SCAN_B 256

// ---------------------------------------------------------------------------
// Edge-index repack: handles both int32 and int64 on-device.
// int64 little-endian with values < 2^31: odd 32-bit words are all 0.
// ---------------------------------------------------------------------------
__global__ void repack_kernel(const unsigned* __restrict__ ei,
                              int* __restrict__ s32, int* __restrict__ d32, int E) {
    __shared__ int is64_s;
    if (threadIdx.x == 0) {
        int z = 1;
        int limit = 2 * E < 128 ? 2 * E : 128;
        for (int i = 1; i < limit; i += 2)
            if (ei[i] != 0u) { z = 0; break; }
        is64_s = z;
    }
    __syncthreads();
    const int is64 = is64_s;
    int e = blockIdx.x * blockDim.x + threadIdx.x;
    if (e < E) {
        if (is64) {
            s32[e] = (int)ei[2 * (long long)e];
            d32[e] = (int)ei[2 * ((long long)E + e)];
        } else {
            s32[e] = (int)ei[e];
            d32[e] = (int)ei[E + e];
        }
    }
}

__global__ void hist_kernel(const int* __restrict__ dst, int* __restrict__ deg, int E) {
    int e = blockIdx.x * blockDim.x + threadIdx.x;
    if (e < E) atomicAdd(&deg[dst[e]], 1);
}

__global__ void dinv_kernel(const int* __restrict__ deg, float* __restrict__ dinv, int N) {
    int i = blockIdx.x * blockDim.x + threadIdx.x;
    if (i < N) dinv[i] = rsqrtf((float)deg[i] + 1.0f);
}

// ---- two-level exclusive scan of deg -> row_ofs (CSR), cur = copy ----------
__global__ void block_sum_kernel(const int* __restrict__ deg, int* __restrict__ blk, int N) {
    __shared__ int s[SCAN_B];
    int i = blockIdx.x * SCAN_B + threadIdx.x;
    s[threadIdx.x] = (i < N) ? deg[i] : 0;
    __syncthreads();
    for (int off = SCAN_B / 2; off > 0; off >>= 1) {
        if (threadIdx.x < off) s[threadIdx.x] += s[threadIdx.x + off];
        __syncthreads();
    }
    if (threadIdx.x == 0) blk[blockIdx.x] = s[0];
}

// single block, 512 threads: exclusive scan of blk[0..nb), nb <= 512
__global__ void scan_blocks_kernel(int* __restrict__ blk, int nb) {
    __shared__ int s[512];
    int t = threadIdx.x;
    s[t] = (t < nb) ? blk[t] : 0;
    __syncthreads();
    for (int off = 1; off < 512; off <<= 1) {
        int add = (t >= off) ? s[t - off] : 0;
        __syncthreads();
        s[t] += add;
        __syncthreads();
    }
    if (t < nb) blk[t] = (t == 0) ? 0 : s[t - 1];
}

__global__ void row_ofs_kernel(const int* __restrict__ deg, const int* __restrict__ blk_ofs,
                               int* __restrict__ row_ofs, int* __restrict__ cur, int N, int E) {
    __shared__ int s[SCAN_B];
    int t = threadIdx.x;
    int i = blockIdx.x * SCAN_B + t;
    int d = (i < N) ? deg[i] : 0;
    s[t] = d;
    __syncthreads();
    for (int off = 1; off < SCAN_B; off <<= 1) {
        int add = (t >= off) ? s[t - off] : 0;
        __syncthreads();
        s[t] += add;
        __syncthreads();
    }
    int ro = blk_ofs[blockIdx.x] + s[t] - d;  // exclusive prefix
    if (i < N) {
        row_ofs[i] = ro;
        cur[i] = ro;
        if (i == N - 1) row_ofs[N] = E;
    }
}

// fill CSR payload: es[p] = {src (bit-cast), norm = dinv[src]*dinv[dst]}
__global__ void fill_kernel(const int* __restrict__ src, const int* __restrict__ dst,
                            const float* __restrict__ dinv, int* __restrict__ cur,
                            float2* __restrict__ es, int E) {
    int e = blockIdx.x * blockDim.x + threadIdx.x;
    if (e < E) {
        int s = src[e], d = dst[e];
        int p = atomicAdd(&cur[d], 1);
        es[p] = make_float2(__int_as_float(s), dinv[s] * dinv[d]);
    }
}

// ---------------------------------------------------------------------------
// Gather aggregation: one wave per node, lanes cover features.
//   agg[n] = sum_{e in in(n)} act(h[src_e]) * nrm_e  +  act(h[n]) * dinv[n]^2 (+ b)
// ---------------------------------------------------------------------------
template <int F, bool ACT, bool BIAS>
__global__ void gather_kernel(const float* __restrict__ h, const float2* __restrict__ es,
                              const int* __restrict__ row_ofs, const float* __restrict__ dinv,
                              const float* __restrict__ b, float* __restrict__ agg, int N) {
    constexpr int C = (F + 63) / 64;
    int gid = blockIdx.x * blockDim.x + threadIdx.x;
    int node = gid >> 6;
    int lane = threadIdx.x & 63;
    if (node >= N) return;
    int beg = row_ofs[node], end = row_ofs[node + 1];
    float di = dinv[node];
    const float* hrow = h + (long long)node * F;
    float acc[C];
#pragma unroll
    for (int c = 0; c < C; ++c) {
        int f = lane + 64 * c;
        if (f < F) {
            float v = hrow[f];
            if (ACT) v = LEAKY(v);
            acc[c] = BIAS ? fmaf(v, di * di, b[f]) : v * di * di;
        } else acc[c] = 0.0f;
    }
    // software pipeline: prefetch next edge descriptor
    float2 e;
    if (beg < end) e = es[beg];
    for (int j = beg; j < end; ++j) {
        float2 ec = e;
        if (j + 1 < end) e = es[j + 1];
        int s = __float_as_int(ec.x);
        float nm = ec.y;
        const float* hs = h + (long long)s * F;
#pragma unroll
        for (int c = 0; c < C; ++c) {
            int f = lane + 64 * c;
            if (f < F) {
                float v = hs[f];
                if (ACT) v = LEAKY(v);
                acc[c] = fmaf(v, nm, acc[c]);
            }
        }
    }
    float* arow = agg + (long long)node * F;
#pragma unroll
    for (int c = 0; c < C; ++c) {
        int f = lane + 64 * c;
        if (f < F) arow[f] = acc[c];
    }
}

// ---------------------------------------------------------------------------
// Register-tiled GEMM: h[n,m] = sum_k act(x[n,k]) * W[k,m] (+ b[m])
// Each thread: NT=4 nodes x MT=4 outputs. W in LDS padded to MP columns.
// Per 4 k-steps: 4 float4 x-loads + 4 ds_read_b128 + 64 FMA.
// ---------------------------------------------------------------------------
template <int K, int M, bool ACT, bool BIAS>
__global__ __launch_bounds__(256) void gemm_tiled(const float* __restrict__ x,
                                                  const float* __restrict__ W,
                                                  const float* __restrict__ b,
                                                  float* __restrict__ h, int N) {
    constexpr int MT = 4;
    constexpr int MC = (M + MT - 1) / MT;  // thread-columns
    constexpr int MP = MC * MT;            // padded M
    constexpr int NR = 256 / MC;           // row-thread groups per block
    constexpr int NT = 4;                  // nodes per thread
    constexpr int BN = NR * NT;            // nodes per block
    static_assert(K % 4 == 0, "K multiple of 4");

    __shared__ float ws[K * MP];
    for (int i = threadIdx.x; i < K * MP; i += 256) {
        int k = i / MP, m = i - k * MP;
        ws[i] = (m < M) ? W[k * M + m] : 0.0f;
    }
    __syncthreads();

    const int c = threadIdx.x % MC;
    const int r = threadIdx.x / MC;
    if (r >= NR) return;  // no barriers after this point
    const int n0 = blockIdx.x * BN + r * NT;

    float acc[NT][MT];
#pragma unroll
    for (int i = 0; i < NT; ++i)
#pragma unroll
        for (int j = 0; j < MT; ++j) {
            int m = c * MT + j;
            acc[i][j] = (BIAS && m < M) ? b[m] : 0.0f;
        }

    for (int k = 0; k < K; k += 4) {
        float4 wv[4];
#pragma unroll
        for (int kk = 0; kk < 4; ++kk)
            wv[kk] = *(const float4*)&ws[(k + kk) * MP + c * MT];
#pragma unroll
        for (int i = 0; i < NT; ++i) {
            int n = n0 + i;
            if (n < N) {
                float4 xv = *(const float4*)&x[(long long)n * K + k];
                if (ACT) {
                    xv.x = LEAKY(xv.x); xv.y = LEAKY(xv.y);
                    xv.z = LEAKY(xv.z); xv.w = LEAKY(xv.w);
                }
                const float xs[4] = {xv.x, xv.y, xv.z, xv.w};
#pragma unroll
                for (int kk = 0; kk < 4; ++kk) {
                    const float* wp = (const float*)&wv[kk];
#pragma unroll
                    for (int j = 0; j < MT; ++j)
                        acc[i][j] = fmaf(xs[kk], wp[j], acc[i][j]);
                }
            }
        }
    }

#pragma unroll
    for (int i = 0; i < NT; ++i) {
        int n = n0 + i;
        if (n >= N) continue;
        int m = c * MT;
        float* hp = h + (long long)n * M + m;
        if (M % 4 == 0) {
            *(float4*)hp = make_float4(acc[i][0], acc[i][1], acc[i][2], acc[i][3]);
        } else if (m + MT <= M) {
            // rows not 16B-aligned (e.g. M=50): float2 pairs (8B-aligned)
            *(float2*)hp = make_float2(acc[i][0], acc[i][1]);
            *(float2*)(hp + 2) = make_float2(acc[i][2], acc[i][3]);
        } else {
#pragma unroll
            for (int j = 0; j < MT; ++j)
                if (m + j < M) hp[j] = acc[i][j];
        }
    }
}

// logits = leaky(a) @ Wl + bl; out = log_softmax(logits)
__global__ void head_kernel(const float* __restrict__ a, const float* __restrict__ Wl,
                            const float* __restrict__ bl, float* __restrict__ out, int N) {
    __shared__ float ws[50 * 10];
    __shared__ float bs[10];
    for (int i = threadIdx.x; i < 500; i += blockDim.x) ws[i] = Wl[i];
    if (threadIdx.x < 10) bs[threadIdx.x] = bl[threadIdx.x];
    __syncthreads();
    int n = blockIdx.x * blockDim.x + threadIdx.x;
    if (n >= N) return;
    float logits[10];
#pragma unroll
    for (int j = 0; j < 10; ++j) logits[j] = bs[j];
    const float* ar = a + (long long)n * 50;
#pragma unroll
    for (int k = 0; k < 50; ++k) {
        float v = LEAKY(ar[k]);
#pragma unroll
        for (int j = 0; j < 10; ++j) logits[j] = fmaf(v, ws[k * 10 + j], logits[j]);
    }
    float mx = logits[0];
#pragma unroll
    for (int j = 1; j < 10; ++j) mx = fmaxf(mx, logits[j]);
    float s = 0.0f;
#pragma unroll
    for (int j = 0; j < 10; ++j) s += __expf(logits[j] - mx);
    float lse = __logf(s) + mx;
    float* op = out + (long long)n * 10;
#pragma unroll
    for (int j = 0; j < 10; ++j) op[j] = logits[j] - lse;
}

extern "C" void kernel_launch(void* const* d_in, const int* in_sizes, int n_in,
                              void* d_out, int out_size, void* d_ws, size_t ws_size,
                              hipStream_t stream) {
    const float* x  = (const float*)d_in[0];
    const unsigned* ei = (const unsigned*)d_in[1];
    const float* W1 = (const float*)d_in[2];
    const float* b1 = (const float*)d_in[3];
    const float* W2 = (const float*)d_in[4];
    const float* b2 = (const float*)d_in[5];
    const float* W3 = (const float*)d_in[6];
    const float* b3 = (const float*)d_in[7];
    const float* Wl = (const float*)d_in[8];
    const float* bl = (const float*)d_in[9];
    float* out = (float*)d_out;

    const int N = in_sizes[0] / 64;
    const int E = in_sizes[1] / 2;

    char* wp = (char*)d_ws;
    auto alloc = [&](size_t bytes) {
        char* p = wp;
        wp += (bytes + 255) & ~(size_t)255;
        return p;
    };
    int*    src     = (int*)alloc((size_t)E * 4);
    int*    dst     = (int*)alloc((size_t)E * 4);
    float2* es      = (float2*)alloc((size_t)E * 8);
    int*    deg     = (int*)alloc((size_t)N * 4);
    float*  dinv    = (float*)alloc((size_t)N * 4);
    int*    row_ofs = (int*)alloc((size_t)(N + 1) * 4);
    int*    cur     = (int*)alloc((size_t)N * 4);
    int*    blk     = (int*)alloc((size_t)512 * 4);
    float*  P       = (float*)alloc((size_t)N * 64 * 4);  // narrow scratch (<=64 wide)
    float*  A       = (float*)alloc((size_t)N * 80 * 4);  // wide scratch (<=80 wide)

    const int B = 256;
    const int nb = (N + SCAN_B - 1) / SCAN_B;  // <= 512 for N <= 131072

    // ---- CSR build (reused by all 3 layers) ----
    hipMemsetAsync(deg, 0, (size_t)N * 4, stream);
    repack_kernel<<<(E + B - 1) / B, B, 0, stream>>>(ei, src, dst, E);
    hist_kernel<<<(E + B - 1) / B, B, 0, stream>>>(dst, deg, E);
    dinv_kernel<<<(N + B - 1) / B, B, 0, stream>>>(deg, dinv, N);
    block_sum_kernel<<<nb, SCAN_B, 0, stream>>>(deg, blk, N);
    scan_blocks_kernel<<<1, 512, 0, stream>>>(blk, nb);
    row_ofs_kernel<<<nb, SCAN_B, 0, stream>>>(deg, blk, row_ofs, cur, N, E);
    fill_kernel<<<(E + B - 1) / B, B, 0, stream>>>(src, dst, dinv, cur, es, E);

    const int gblocks = (N * 64 + B - 1) / B;  // one wave per node

    // block counts for gemm_tiled: BN = (256 / ceil(M/4)) * 4 nodes per block
    auto gb = [&](int M) {
        int MC = (M + 3) / 4;
        int BN = (256 / MC) * 4;
        return (N + BN - 1) / BN;
    };

    // L1: agg(x) first (64-wide < 80-wide), then GEMM(+b1)
    gather_kernel<64, false, false><<<gblocks, B, 0, stream>>>(x, es, row_ofs, dinv, nullptr, P, N);
    gemm_tiled<64, 80, false, true><<<gb(80), B, 0, stream>>>(P, W1, b1, A, N);

    // L2: GEMM first (40-wide < 80-wide): H = leaky(A) @ W2, then agg(+b2)
    gemm_tiled<80, 40, true, false><<<gb(40), B, 0, stream>>>(A, W2, nullptr, P, N);
    gather_kernel<40, false, true><<<gblocks, B, 0, stream>>>(P, es, row_ofs, dinv, b2, A, N);

    // L3: agg(leaky(A)) first (40-wide < 50-wide), then GEMM(+b3)
    gather_kernel<40, true, false><<<gblocks, B, 0, stream>>>(A, es, row_ofs, dinv, nullptr, P, N);
    gemm_tiled<40, 50, false, true><<<gb(50), B, 0, stream>>>(P, W3, b3, A, N);

    // head: leaky -> 50x10 linear -> log_softmax
    head_kernel<<<(N + B - 1) / B, B, 0, stream>>>(A, Wl, bl, out, N);
}

// Round 4
// 403.148 us; speedup vs baseline: 6.1776x; 1.2557x over previous
//
#include <hip/hip_runtime.h>

#define LEAKY(v) ((v) > 0.0f ? (v) : 0.01f * (v))
#define SCAN_B 256

// ---------------------------------------------------------------------------
// Edge-index repack (+degree histogram fused): handles int32 and int64.
// int64 little-endian with values < 2^31: odd 32-bit words are all 0.
// ---------------------------------------------------------------------------
__global__ void repack_kernel(const unsigned* __restrict__ ei,
                              int* __restrict__ s32, int* __restrict__ d32,
                              int* __restrict__ deg, int E) {
    __shared__ int is64_s;
    if (threadIdx.x == 0) {
        int z = 1;
        int limit = 2 * E < 128 ? 2 * E : 128;
        for (int i = 1; i < limit; i += 2)
            if (ei[i] != 0u) { z = 0; break; }
        is64_s = z;
    }
    __syncthreads();
    const int is64 = is64_s;
    int e = blockIdx.x * blockDim.x + threadIdx.x;
    if (e < E) {
        int s, d;
        if (is64) {
            s = (int)ei[2 * (long long)e];
            d = (int)ei[2 * ((long long)E + e)];
        } else {
            s = (int)ei[e];
            d = (int)ei[E + e];
        }
        s32[e] = s;
        d32[e] = d;
        atomicAdd(&deg[d], 1);
    }
}

__global__ void dinv_kernel(const int* __restrict__ deg, float* __restrict__ dinv, int N) {
    int i = blockIdx.x * blockDim.x + threadIdx.x;
    if (i < N) dinv[i] = rsqrtf((float)deg[i] + 1.0f);
}

// ---- two-level exclusive scan of deg -> row_ofs (CSR), cur = copy ----------
__global__ void block_sum_kernel(const int* __restrict__ deg, int* __restrict__ blk, int N) {
    __shared__ int s[SCAN_B];
    int i = blockIdx.x * SCAN_B + threadIdx.x;
    s[threadIdx.x] = (i < N) ? deg[i] : 0;
    __syncthreads();
    for (int off = SCAN_B / 2; off > 0; off >>= 1) {
        if (threadIdx.x < off) s[threadIdx.x] += s[threadIdx.x + off];
        __syncthreads();
    }
    if (threadIdx.x == 0) blk[blockIdx.x] = s[0];
}

// single block, 512 threads: exclusive scan of blk[0..nb), nb <= 512
__global__ void scan_blocks_kernel(int* __restrict__ blk, int nb) {
    __shared__ int s[512];
    int t = threadIdx.x;
    s[t] = (t < nb) ? blk[t] : 0;
    __syncthreads();
    for (int off = 1; off < 512; off <<= 1) {
        int add = (t >= off) ? s[t - off] : 0;
        __syncthreads();
        s[t] += add;
        __syncthreads();
    }
    if (t < nb) blk[t] = (t == 0) ? 0 : s[t - 1];
}

__global__ void row_ofs_kernel(const int* __restrict__ deg, const int* __restrict__ blk_ofs,
                               int* __restrict__ row_ofs, int* __restrict__ cur, int N, int E) {
    __shared__ int s[SCAN_B];
    int t = threadIdx.x;
    int i = blockIdx.x * SCAN_B + t;
    int d = (i < N) ? deg[i] : 0;
    s[t] = d;
    __syncthreads();
    for (int off = 1; off < SCAN_B; off <<= 1) {
        int add = (t >= off) ? s[t - off] : 0;
        __syncthreads();
        s[t] += add;
        __syncthreads();
    }
    int ro = blk_ofs[blockIdx.x] + s[t] - d;  // exclusive prefix
    if (i < N) {
        row_ofs[i] = ro;
        cur[i] = ro;
        if (i == N - 1) row_ofs[N] = E;
    }
}

// fill CSR payload: es[p] = {src (bit-cast), norm = dinv[src]*dinv[dst]}
__global__ void fill_kernel(const int* __restrict__ src, const int* __restrict__ dst,
                            const float* __restrict__ dinv, int* __restrict__ cur,
                            float2* __restrict__ es, int E) {
    int e = blockIdx.x * blockDim.x + threadIdx.x;
    if (e < E) {
        int s = src[e], d = dst[e];
        int p = atomicAdd(&cur[d], 1);
        es[p] = make_float2(__int_as_float(s), dinv[s] * dinv[d]);
    }
}

// ---------------------------------------------------------------------------
// F=64 gather: wave per node; 4 groups x 16 lanes x float4; 8 edges in flight.
// agg[n] = sum_e act(h[src_e])*nrm_e + act(h[n])*dinv[n]^2 (+ b)
// ---------------------------------------------------------------------------
template <bool ACT, bool BIAS>
__global__ __launch_bounds__(256) void gather64_kernel(
    const float* __restrict__ h, const float2* __restrict__ es,
    const int* __restrict__ row_ofs, const float* __restrict__ dinv,
    const float* __restrict__ b, float* __restrict__ agg, int N) {
    int gid = blockIdx.x * blockDim.x + threadIdx.x;
    int node = gid >> 6;
    if (node >= N) return;
    int lane = threadIdx.x & 63;
    int g = lane >> 4, l = lane & 15;
    int beg = row_ofs[node], end = row_ofs[node + 1];

    float4 acc = make_float4(0.f, 0.f, 0.f, 0.f);
    for (int base = beg; base < end; base += 8) {
        int j0 = base + g;
        int j1 = base + 4 + g;
        int j0c = j0 < end ? j0 : beg;
        int j1c = j1 < end ? j1 : beg;
        float2 e0 = es[j0c];
        float2 e1 = es[j1c];
        int s0 = __float_as_int(e0.x);
        int s1 = __float_as_int(e1.x);
        float n0 = j0 < end ? e0.y : 0.0f;
        float n1 = j1 < end ? e1.y : 0.0f;
        float4 h0 = *(const float4*)&h[(size_t)s0 * 64 + 4 * l];
        float4 h1 = *(const float4*)&h[(size_t)s1 * 64 + 4 * l];
        if (ACT) {
            h0.x = LEAKY(h0.x); h0.y = LEAKY(h0.y); h0.z = LEAKY(h0.z); h0.w = LEAKY(h0.w);
            h1.x = LEAKY(h1.x); h1.y = LEAKY(h1.y); h1.z = LEAKY(h1.z); h1.w = LEAKY(h1.w);
        }
        acc.x = fmaf(h0.x, n0, acc.x); acc.y = fmaf(h0.y, n0, acc.y);
        acc.z = fmaf(h0.z, n0, acc.z); acc.w = fmaf(h0.w, n0, acc.w);
        acc.x = fmaf(h1.x, n1, acc.x); acc.y = fmaf(h1.y, n1, acc.y);
        acc.z = fmaf(h1.z, n1, acc.z); acc.w = fmaf(h1.w, n1, acc.w);
    }
    // butterfly-reduce across the 4 groups (xor 16, 32)
#pragma unroll
    for (int mask = 16; mask <= 32; mask <<= 1) {
        acc.x += __shfl_xor(acc.x, mask);
        acc.y += __shfl_xor(acc.y, mask);
        acc.z += __shfl_xor(acc.z, mask);
        acc.w += __shfl_xor(acc.w, mask);
    }
    if (g == 0) {
        float di = dinv[node];
        float s2 = di * di;
        float4 sv = *(const float4*)&h[(size_t)node * 64 + 4 * l];
        if (ACT) { sv.x = LEAKY(sv.x); sv.y = LEAKY(sv.y); sv.z = LEAKY(sv.z); sv.w = LEAKY(sv.w); }
        acc.x = fmaf(sv.x, s2, acc.x); acc.y = fmaf(sv.y, s2, acc.y);
        acc.z = fmaf(sv.z, s2, acc.z); acc.w = fmaf(sv.w, s2, acc.w);
        if (BIAS) {
            float4 bv = *(const float4*)&b[4 * l];
            acc.x += bv.x; acc.y += bv.y; acc.z += bv.z; acc.w += bv.w;
        }
        *(float4*)&agg[(size_t)node * 64 + 4 * l] = acc;
    }
}

// ---------------------------------------------------------------------------
// F=40 gather: wave per node; 6 groups x 10 lanes x float4 (lanes 60-63 idle);
// 12 edges in flight. Rows are 160B (16B-aligned).
// ---------------------------------------------------------------------------
template <bool ACT, bool BIAS>
__global__ __launch_bounds__(256) void gather40_kernel(
    const float* __restrict__ h, const float2* __restrict__ es,
    const int* __restrict__ row_ofs, const float* __restrict__ dinv,
    const float* __restrict__ b, float* __restrict__ agg, int N) {
    int gid = blockIdx.x * blockDim.x + threadIdx.x;
    int node = gid >> 6;
    if (node >= N) return;
    int lane = threadIdx.x & 63;
    int g = lane / 10;          // 0..6 (6 => idle lanes 60-63)
    int l = lane - g * 10;      // 0..9
    bool lv = lane < 60;
    int beg = row_ofs[node], end = row_ofs[node + 1];

    float4 acc = make_float4(0.f, 0.f, 0.f, 0.f);
    for (int base = beg; base < end; base += 12) {
        int j0 = base + g;
        int j1 = base + 6 + g;
        bool v0 = lv && (j0 < end);
        bool v1 = lv && (j1 < end);
        int j0c = v0 ? j0 : beg;
        int j1c = v1 ? j1 : beg;
        float2 e0 = es[j0c];
        float2 e1 = es[j1c];
        int s0 = __float_as_int(e0.x);
        int s1 = __float_as_int(e1.x);
        float n0 = v0 ? e0.y : 0.0f;
        float n1 = v1 ? e1.y : 0.0f;
        float4 h0 = *(const float4*)&h[(size_t)s0 * 40 + 4 * l];
        float4 h1 = *(const float4*)&h[(size_t)s1 * 40 + 4 * l];
        if (ACT) {
            h0.x = LEAKY(h0.x); h0.y = LEAKY(h0.y); h0.z = LEAKY(h0.z); h0.w = LEAKY(h0.w);
            h1.x = LEAKY(h1.x); h1.y = LEAKY(h1.y); h1.z = LEAKY(h1.z); h1.w = LEAKY(h1.w);
        }
        acc.x = fmaf(h0.x, n0, acc.x); acc.y = fmaf(h0.y, n0, acc.y);
        acc.z = fmaf(h0.z, n0, acc.z); acc.w = fmaf(h0.w, n0, acc.w);
        acc.x = fmaf(h1.x, n1, acc.x); acc.y = fmaf(h1.y, n1, acc.y);
        acc.z = fmaf(h1.z, n1, acc.z); acc.w = fmaf(h1.w, n1, acc.w);
    }
    // combine 6 groups: read ORIGINAL acc of lanes +10..+50, then add
    float4 r = acc;
#pragma unroll
    for (int o = 10; o <= 50; o += 10) {
        r.x += __shfl(acc.x, lane + o);
        r.y += __shfl(acc.y, lane + o);
        r.z += __shfl(acc.z, lane + o);
        r.w += __shfl(acc.w, lane + o);
    }
    if (lane < 10) {
        float di = dinv[node];
        float s2 = di * di;
        float4 sv = *(const float4*)&h[(size_t)node * 40 + 4 * l];
        if (ACT) { sv.x = LEAKY(sv.x); sv.y = LEAKY(sv.y); sv.z = LEAKY(sv.z); sv.w = LEAKY(sv.w); }
        r.x = fmaf(sv.x, s2, r.x); r.y = fmaf(sv.y, s2, r.y);
        r.z = fmaf(sv.z, s2, r.z); r.w = fmaf(sv.w, s2, r.w);
        if (BIAS) {
            float4 bv = *(const float4*)&b[4 * l];
            r.x += bv.x; r.y += bv.y; r.z += bv.z; r.w += bv.w;
        }
        *(float4*)&agg[(size_t)node * 40 + 4 * l] = r;
    }
}

// ---------------------------------------------------------------------------
// Register-tiled GEMM: h[n,m] = sum_k act(x[n,k]) * W[k,m] (+ b[m])
// ---------------------------------------------------------------------------
template <int K, int M, bool ACT, bool BIAS>
__global__ __launch_bounds__(256) void gemm_tiled(const float* __restrict__ x,
                                                  const float* __restrict__ W,
                                                  const float* __restrict__ b,
                                                  float* __restrict__ h, int N) {
    constexpr int MT = 4;
    constexpr int MC = (M + MT - 1) / MT;  // thread-columns
    constexpr int MP = MC * MT;            // padded M
    constexpr int NR = 256 / MC;           // row-thread groups per block
    constexpr int NT = 4;                  // nodes per thread
    constexpr int BN = NR * NT;            // nodes per block
    static_assert(K % 4 == 0, "K multiple of 4");

    __shared__ float ws[K * MP];
    for (int i = threadIdx.x; i < K * MP; i += 256) {
        int k = i / MP, m = i - k * MP;
        ws[i] = (m < M) ? W[k * M + m] : 0.0f;
    }
    __syncthreads();

    const int c = threadIdx.x % MC;
    const int r = threadIdx.x / MC;
    if (r >= NR) return;  // no barriers after this point
    const int n0 = blockIdx.x * BN + r * NT;

    float acc[NT][MT];
#pragma unroll
    for (int i = 0; i < NT; ++i)
#pragma unroll
        for (int j = 0; j < MT; ++j) {
            int m = c * MT + j;
            acc[i][j] = (BIAS && m < M) ? b[m] : 0.0f;
        }

    for (int k = 0; k < K; k += 4) {
        float4 wv[4];
#pragma unroll
        for (int kk = 0; kk < 4; ++kk)
            wv[kk] = *(const float4*)&ws[(k + kk) * MP + c * MT];
#pragma unroll
        for (int i = 0; i < NT; ++i) {
            int n = n0 + i;
            if (n < N) {
                float4 xv = *(const float4*)&x[(long long)n * K + k];
                if (ACT) {
                    xv.x = LEAKY(xv.x); xv.y = LEAKY(xv.y);
                    xv.z = LEAKY(xv.z); xv.w = LEAKY(xv.w);
                }
                const float xs[4] = {xv.x, xv.y, xv.z, xv.w};
#pragma unroll
                for (int kk = 0; kk < 4; ++kk) {
                    const float* wp = (const float*)&wv[kk];
#pragma unroll
                    for (int j = 0; j < MT; ++j)
                        acc[i][j] = fmaf(xs[kk], wp[j], acc[i][j]);
                }
            }
        }
    }

#pragma unroll
    for (int i = 0; i < NT; ++i) {
        int n = n0 + i;
        if (n >= N) continue;
        int m = c * MT;
        float* hp = h + (long long)n * M + m;
        if (M % 4 == 0) {
            *(float4*)hp = make_float4(acc[i][0], acc[i][1], acc[i][2], acc[i][3]);
        } else if (m + MT <= M) {
            *(float2*)hp = make_float2(acc[i][0], acc[i][1]);
            *(float2*)(hp + 2) = make_float2(acc[i][2], acc[i][3]);
        } else {
#pragma unroll
            for (int j = 0; j < MT; ++j)
                if (m + j < M) hp[j] = acc[i][j];
        }
    }
}

// logits = leaky(a) @ Wl + bl; out = log_softmax(logits)
__global__ void head_kernel(const float* __restrict__ a, const float* __restrict__ Wl,
                            const float* __restrict__ bl, float* __restrict__ out, int N) {
    __shared__ float ws[50 * 10];
    __shared__ float bs[10];
    for (int i = threadIdx.x; i < 500; i += blockDim.x) ws[i] = Wl[i];
    if (threadIdx.x < 10) bs[threadIdx.x] = bl[threadIdx.x];
    __syncthreads();
    int n = blockIdx.x * blockDim.x + threadIdx.x;
    if (n >= N) return;
    float logits[10];
#pragma unroll
    for (int j = 0; j < 10; ++j) logits[j] = bs[j];
    const float* ar = a + (long long)n * 50;
#pragma unroll
    for (int k = 0; k < 50; ++k) {
        float v = LEAKY(ar[k]);
#pragma unroll
        for (int j = 0; j < 10; ++j) logits[j] = fmaf(v, ws[k * 10 + j], logits[j]);
    }
    float mx = logits[0];
#pragma unroll
    for (int j = 1; j < 10; ++j) mx = fmaxf(mx, logits[j]);
    float s = 0.0f;
#pragma unroll
    for (int j = 0; j < 10; ++j) s += __expf(logits[j] - mx);
    float lse = __logf(s) + mx;
    float* op = out + (long long)n * 10;
#pragma unroll
    for (int j = 0; j < 10; ++j) op[j] = logits[j] - lse;
}

extern "C" void kernel_launch(void* const* d_in, const int* in_sizes, int n_in,
                              void* d_out, int out_size, void* d_ws, size_t ws_size,
                              hipStream_t stream) {
    const float* x  = (const float*)d_in[0];
    const unsigned* ei = (const unsigned*)d_in[1];
    const float* W1 = (const float*)d_in[2];
    const float* b1 = (const float*)d_in[3];
    const float* W2 = (const float*)d_in[4];
    const float* b2 = (const float*)d_in[5];
    const float* W3 = (const float*)d_in[6];
    const float* b3 = (const float*)d_in[7];
    const float* Wl = (const float*)d_in[8];
    const float* bl = (const float*)d_in[9];
    float* out = (float*)d_out;

    const int N = in_sizes[0] / 64;
    const int E = in_sizes[1] / 2;

    char* wp = (char*)d_ws;
    auto alloc = [&](size_t bytes) {
        char* p = wp;
        wp += (bytes + 255) & ~(size_t)255;
        return p;
    };
    int*    src     = (int*)alloc((size_t)E * 4);
    int*    dst     = (int*)alloc((size_t)E * 4);
    float2* es      = (float2*)alloc((size_t)E * 8);
    int*    deg     = (int*)alloc((size_t)N * 4);
    float*  dinv    = (float*)alloc((size_t)N * 4);
    int*    row_ofs = (int*)alloc((size_t)(N + 1) * 4);
    int*    cur     = (int*)alloc((size_t)N * 4);
    int*    blk     = (int*)alloc((size_t)512 * 4);
    float*  P       = (float*)alloc((size_t)N * 64 * 4);  // narrow scratch (<=64 wide)
    float*  A       = (float*)alloc((size_t)N * 80 * 4);  // wide scratch (<=80 wide)

    const int B = 256;
    const int nb = (N + SCAN_B - 1) / SCAN_B;  // <= 512 for N <= 131072

    // ---- CSR build (reused by all 3 layers) ----
    hipMemsetAsync(deg, 0, (size_t)N * 4, stream);
    repack_kernel<<<(E + B - 1) / B, B, 0, stream>>>(ei, src, dst, deg, E);
    dinv_kernel<<<(N + B - 1) / B, B, 0, stream>>>(deg, dinv, N);
    block_sum_kernel<<<nb, SCAN_B, 0, stream>>>(deg, blk, N);
    scan_blocks_kernel<<<1, 512, 0, stream>>>(blk, nb);
    row_ofs_kernel<<<nb, SCAN_B, 0, stream>>>(deg, blk, row_ofs, cur, N, E);
    fill_kernel<<<(E + B - 1) / B, B, 0, stream>>>(src, dst, dinv, cur, es, E);

    const int gblocks = (N * 64 + B - 1) / B;  // one wave per node

    // block counts for gemm_tiled: BN = (256 / ceil(M/4)) * 4 nodes per block
    auto gb = [&](int M) {
        int MC = (M + 3) / 4;
        int BN = (256 / MC) * 4;
        return (N + BN - 1) / BN;
    };

    // L1: agg(x) first (64-wide < 80-wide), then GEMM(+b1)
    gather64_kernel<false, false><<<gblocks, B, 0, stream>>>(x, es, row_ofs, dinv, nullptr, P, N);
    gemm_tiled<64, 80, false, true><<<gb(80), B, 0, stream>>>(P, W1, b1, A, N);

    // L2: GEMM first (40-wide < 80-wide): H = leaky(A) @ W2, then agg(+b2)
    gemm_tiled<80, 40, true, false><<<gb(40), B, 0, stream>>>(A, W2, nullptr, P, N);
    gather40_kernel<false, true><<<gblocks, B, 0, stream>>>(P, es, row_ofs, dinv, b2, A, N);

    // L3: agg(leaky(A)) first (40-wide < 50-wide), then GEMM(+b3)
    gather40_kernel<true, false><<<gblocks, B, 0, stream>>>(A, es, row_ofs, dinv, nullptr, P, N);
    gemm_tiled<40, 50, false, true><<<gb(50), B, 0, stream>>>(P, W3, b3, A, N);

    // head: leaky -> 50x10 linear -> log_softmax
    head_kernel<<<(N + B - 1) / B, B, 0, stream>>>(A, Wl, bl, out, N);
}